// Round 23
// baseline (352.870 us; speedup 1.0000x reference)
//
#include <hip/hip_runtime.h>
#include <hip/hip_bf16.h>

#define D_MODEL 1024
#define NUM_HEADS 16
#define D_K 64
#define B_ 4
#define L_ 2048

typedef _Float16 f16x8 __attribute__((ext_vector_type(8)));
typedef _Float16 f16x4 __attribute__((ext_vector_type(4)));
typedef float f32x4 __attribute__((ext_vector_type(4)));

__device__ __forceinline__ float fexp2(float x) {
    float r;
    asm("v_exp_f32 %0, %1" : "=v"(r) : "v"(x));
    return r;
}

__device__ __forceinline__ float fmax3(float a, float b, float c) {
    float r;
    asm("v_max3_f32 %0, %1, %2, %3" : "=v"(r) : "v"(a), "v"(b), "v"(c));
    return r;
}

__device__ __forceinline__ f16x4 pack4(float p0, float p1, float p2, float p3) {
    auto lo = __builtin_amdgcn_cvt_pkrtz(p0, p1);
    auto hi = __builtin_amdgcn_cvt_pkrtz(p2, p3);
    f16x4 pk;
    pk[0] = (_Float16)lo[0]; pk[1] = (_Float16)lo[1];
    pk[2] = (_Float16)hi[0]; pk[3] = (_Float16)hi[1];
    return pk;
}

// ---------------------------------------------------------------------------
// W[k][n] fp32 -> Wt[n][k] fp16
// ---------------------------------------------------------------------------
__global__ __launch_bounds__(256) void transp_cast4_kernel(
    const float* __restrict__ w0, const float* __restrict__ w1,
    const float* __restrict__ w2, const float* __restrict__ w3,
    _Float16* __restrict__ t0, _Float16* __restrict__ t1,
    _Float16* __restrict__ t2, _Float16* __restrict__ t3)
{
    const float* W = blockIdx.z == 0 ? w0 : blockIdx.z == 1 ? w1
                   : blockIdx.z == 2 ? w2 : w3;
    _Float16* Wt = blockIdx.z == 0 ? t0 : blockIdx.z == 1 ? t1
                 : blockIdx.z == 2 ? t2 : t3;
    __shared__ _Float16 Ls[64][72];
    const int n0 = blockIdx.x * 64, k0 = blockIdx.y * 64;
    const int tid = threadIdx.x;
#pragma unroll
    for (int i = 0; i < 4; ++i) {
        int idx = tid + 256 * i;
        int k = idx >> 4, c4 = (idx & 15) << 2;
        float4 wv = *(const float4*)&W[(size_t)(k0 + k) * D_MODEL + n0 + c4];
        Ls[c4 + 0][k] = (_Float16)wv.x;
        Ls[c4 + 1][k] = (_Float16)wv.y;
        Ls[c4 + 2][k] = (_Float16)wv.z;
        Ls[c4 + 3][k] = (_Float16)wv.w;
    }
    __syncthreads();
#pragma unroll
    for (int i = 0; i < 2; ++i) {
        int idx = tid + 256 * i;
        int n = idx >> 3, k8 = (idx & 7) << 3;
        f16x8 v;
#pragma unroll
        for (int j = 0; j < 8; ++j) v[j] = Ls[n][k8 + j];
        *(f16x8*)&Wt[(size_t)(n0 + n) * D_MODEL + k0 + k8] = v;
    }
}

// ---------------------------------------------------------------------------
// MFMA GEMM core, 512 thr / 8 waves, 128x128 tile, fused fp32-A cast,
// B double-buffered with issue-early.
// ---------------------------------------------------------------------------
__device__ __forceinline__ void gemm_core_f32A8(
    const float* __restrict__ X, const _Float16* __restrict__ Wt,
    _Float16* As, _Float16* Bs0, _Float16* Bs1, f32x4 (&acc)[2][4],
    int m0, int n0, int K, int tid)
{
    const int lane = tid & 63, w = tid >> 6;      // w 0..7
    const int g = lane >> 4, c = lane & 15;
    const int wr = w >> 1, wc = w & 1;            // wr 0..3, wc 0..1
    const int srow = lane >> 3, sslot = lane & 7;
    const int gslot = (sslot ^ (srow & 7)) << 3;

    float4 ar[2][2];
#pragma unroll
    for (int i = 0; i < 2; ++i) {
        int r = (w * 2 + i) * 8 + srow;
        const float* xp = &X[(size_t)(m0 + r) * K + 8 * sslot];
        ar[i][0] = *(const float4*)xp;
        ar[i][1] = *(const float4*)(xp + 4);
    }
#pragma unroll
    for (int i = 0; i < 2; ++i) {
        int chunk = w * 2 + i;
        int r = chunk * 8 + srow;
        const _Float16* gq = &Wt[(size_t)(n0 + r) * K + gslot];
        __builtin_amdgcn_global_load_lds(
            (const __attribute__((address_space(1))) void*)gq,
            (__attribute__((address_space(3))) void*)&Bs0[chunk * 512],
            16, 0, 0);
    }

    for (int kt = 0; kt < K; kt += 64) {
        _Float16* Bcur = ((kt >> 6) & 1) ? Bs1 : Bs0;
        _Float16* Bnxt = ((kt >> 6) & 1) ? Bs0 : Bs1;

#pragma unroll
        for (int i = 0; i < 2; ++i) {
            int r = (w * 2 + i) * 8 + srow;
            f16x4 ca = pack4(ar[i][0].x, ar[i][0].y, ar[i][0].z, ar[i][0].w);
            f16x4 cb = pack4(ar[i][1].x, ar[i][1].y, ar[i][1].z, ar[i][1].w);
            f16x8 cc;
            cc[0] = ca[0]; cc[1] = ca[1]; cc[2] = ca[2]; cc[3] = ca[3];
            cc[4] = cb[0]; cc[5] = cb[1]; cc[6] = cb[2]; cc[7] = cb[3];
            *(f16x8*)&As[r * 64 + ((sslot ^ (r & 7)) << 3)] = cc;
        }
        __syncthreads();

        int ktn = kt + 64;
        if (ktn < K) {
#pragma unroll
            for (int i = 0; i < 2; ++i) {
                int chunk = w * 2 + i;
                int r = chunk * 8 + srow;
                const _Float16* gq = &Wt[(size_t)(n0 + r) * K + ktn + gslot];
                __builtin_amdgcn_global_load_lds(
                    (const __attribute__((address_space(1))) void*)gq,
                    (__attribute__((address_space(3))) void*)&Bnxt[chunk * 512],
                    16, 0, 0);
            }
#pragma unroll
            for (int i = 0; i < 2; ++i) {
                int r = (w * 2 + i) * 8 + srow;
                const float* xp = &X[(size_t)(m0 + r) * K + ktn + 8 * sslot];
                ar[i][0] = *(const float4*)xp;
                ar[i][1] = *(const float4*)(xp + 4);
            }
        }

#pragma unroll
        for (int kk = 0; kk < 2; ++kk) {
            f16x8 a[2], bf[4];
#pragma unroll
            for (int mi = 0; mi < 2; ++mi) {
                int row = wr * 32 + mi * 16 + c;
                int ks = kk * 4 + g;
                a[mi] = *(const f16x8*)&As[row * 64 + ((ks ^ (row & 7)) << 3)];
            }
#pragma unroll
            for (int ni = 0; ni < 4; ++ni) {
                int row = wc * 64 + ni * 16 + c;
                int ks = kk * 4 + g;
                bf[ni] = *(const f16x8*)&Bcur[row * 64 + ((ks ^ (row & 7)) << 3)];
            }
#pragma unroll
            for (int mi = 0; mi < 2; ++mi)
#pragma unroll
                for (int ni = 0; ni < 4; ++ni)
                    acc[mi][ni] = __builtin_amdgcn_mfma_f32_16x16x32_f16(
                        a[mi], bf[ni], acc[mi][ni], 0, 0, 0);
        }
        __syncthreads();
    }
}

// ---------------------------------------------------------------------------
// fp16-A GEMM core, 512 thr / 8 waves, 128x128 (for the O projection)
// ---------------------------------------------------------------------------
__device__ __forceinline__ void gemm_core8(
    const _Float16* __restrict__ Xh, const _Float16* __restrict__ Wt,
    _Float16* As, _Float16* Bs, f32x4 (&acc)[2][4],
    int m0, int n0, int K, int tid)
{
    const int lane = tid & 63, w = tid >> 6;
    const int g = lane >> 4, c = lane & 15;
    const int wr = w >> 1, wc = w & 1;
    const int srow = lane >> 3, sslot = lane & 7;
    const int gslot = (sslot ^ (srow & 7)) << 3;

    for (int kt = 0; kt < K; kt += 64) {
#pragma unroll
        for (int i = 0; i < 2; ++i) {
            int chunk = w * 2 + i;
            int r = chunk * 8 + srow;
            const _Float16* gp = &Xh[(size_t)(m0 + r) * K + kt + gslot];
            __builtin_amdgcn_global_load_lds(
                (const __attribute__((address_space(1))) void*)gp,
                (__attribute__((address_space(3))) void*)&As[chunk * 512],
                16, 0, 0);
            const _Float16* gq = &Wt[(size_t)(n0 + r) * K + kt + gslot];
            __builtin_amdgcn_global_load_lds(
                (const __attribute__((address_space(1))) void*)gq,
                (__attribute__((address_space(3))) void*)&Bs[chunk * 512],
                16, 0, 0);
        }
        __syncthreads();

#pragma unroll
        for (int kk = 0; kk < 2; ++kk) {
            f16x8 a[2], bf[4];
#pragma unroll
            for (int mi = 0; mi < 2; ++mi) {
                int row = wr * 32 + mi * 16 + c;
                int ks = kk * 4 + g;
                a[mi] = *(const f16x8*)&As[row * 64 + ((ks ^ (row & 7)) << 3)];
            }
#pragma unroll
            for (int ni = 0; ni < 4; ++ni) {
                int row = wc * 64 + ni * 16 + c;
                int ks = kk * 4 + g;
                bf[ni] = *(const f16x8*)&Bs[row * 64 + ((ks ^ (row & 7)) << 3)];
            }
#pragma unroll
            for (int mi = 0; mi < 2; ++mi)
#pragma unroll
                for (int ni = 0; ni < 4; ++ni)
                    acc[mi][ni] = __builtin_amdgcn_mfma_f32_16x16x32_f16(
                        a[mi], bf[ni], acc[mi][ni], 0, 0, 0);
        }
        __syncthreads();
    }
}

// ---------------------------------------------------------------------------
// Merged Q/K/V projection GEMMs, 512 thr / 8 waves, fused cast + dbuf-B.
// ---------------------------------------------------------------------------
__global__ __launch_bounds__(512, 4) void gemm_qkv_kernel(
    const float* __restrict__ xq, const float* __restrict__ xk,
    const float* __restrict__ xv, const _Float16* __restrict__ wqt,
    const _Float16* __restrict__ wkt, const _Float16* __restrict__ wvt,
    const float* __restrict__ bq, const float* __restrict__ bk,
    const float* __restrict__ bv, _Float16* __restrict__ qh,
    _Float16* __restrict__ kh, _Float16* __restrict__ vt, float qscale)
{
    __shared__ _Float16 LB[128 * 192];   // As | Bs0 | Bs1 (48KB)
    _Float16* As = LB;
    _Float16* Bs0 = LB + 128 * 64;
    _Float16* Bs1 = LB + 128 * 128;

    int flat = blockIdx.x + 8 * blockIdx.y + 512 * blockIdx.z;
    int swz = (flat & 7) * 192 + (flat >> 3);     // 1536/8 = 192
    const int n0 = (swz & 7) * 128;
    const int m0 = ((swz >> 3) & 63) * 128;
    const int z = swz >> 9;

    const float* X = z == 0 ? xq : z == 1 ? xk : xv;
    const _Float16* Wt = z == 0 ? wqt : z == 1 ? wkt : wvt;
    const float* bias = z == 0 ? bq : z == 1 ? bk : bv;

    const int tid = threadIdx.x;
    const int lane = tid & 63, w = tid >> 6;
    const int g = lane >> 4, c = lane & 15;
    const int wr = w >> 1, wc = w & 1;

    f32x4 acc[2][4] = {};
    gemm_core_f32A8(X, Wt, As, Bs0, Bs1, acc, m0, n0, D_MODEL, tid);

    if (z != 2) {
        _Float16* outH = z == 0 ? qh : kh;
        const float scale = z == 0 ? qscale : 1.0f;
#pragma unroll
        for (int mi = 0; mi < 2; ++mi)
#pragma unroll
            for (int ni = 0; ni < 4; ++ni)
#pragma unroll
                for (int r = 0; r < 4; ++r) {
                    int m = m0 + wr * 32 + mi * 16 + 4 * g + r;
                    int n = n0 + wc * 64 + ni * 16 + c;
                    float v = (acc[mi][ni][r] + bias[n]) * scale;
                    int b = m >> 11, l = m & (L_ - 1);
                    int hh = n >> 6, dk = n & 63;
                    outH[(((size_t)b * NUM_HEADS + hh) * L_ + l) * D_K + dk] =
                        (_Float16)v;
                }
    } else {
        __syncthreads();
#pragma unroll
        for (int mi = 0; mi < 2; ++mi)
#pragma unroll
            for (int ni = 0; ni < 4; ++ni)
#pragma unroll
                for (int r = 0; r < 4; ++r) {
                    int ml = wr * 32 + mi * 16 + 4 * g + r;
                    int nl = wc * 64 + ni * 16 + c;
                    LB[nl * 128 + (ml ^ ((nl & 7) << 3))] =
                        (_Float16)(acc[mi][ni][r] + bias[n0 + nl]);
                }
        __syncthreads();
#pragma unroll
        for (int it = 0; it < 4; ++it) {
            int chunk = tid + 512 * it;
            int nl = chunk >> 4;
            int mc = (chunk & 15) << 3;
            f16x8 vv = *(const f16x8*)&LB[nl * 128 + (mc ^ ((nl & 7) << 3))];
            int n = n0 + nl;
            int hh = n >> 6, dk = n & 63;
            int mstart = m0 + mc;
            int bb = mstart >> 11, l = mstart & (L_ - 1);
            *(f16x8*)&vt[(((size_t)bb * NUM_HEADS + hh) * D_K + dk) * L_ + l] = vv;
        }
    }
}

// ---------------------------------------------------------------------------
// O-projection GEMM, 512 thr / 8 waves (XCD-swizzled), fp32 flat output
// ---------------------------------------------------------------------------
__global__ __launch_bounds__(512, 4) void gemm_o_kernel(
    const _Float16* __restrict__ Xh, const _Float16* __restrict__ Wt,
    const float* __restrict__ bias, float* __restrict__ outF, int M, int N, int K)
{
    __shared__ _Float16 As[128 * 64];
    __shared__ _Float16 Bs[128 * 64];
    int flat = blockIdx.x + 8 * blockIdx.y;
    int swz = (flat & 7) * 64 + (flat >> 3);
    const int n0 = (swz & 7) * 128;
    const int m0 = (swz >> 3) * 128;

    const int tid = threadIdx.x;
    const int lane = tid & 63, w = tid >> 6;
    const int g = lane >> 4, c = lane & 15;
    const int wr = w >> 1, wc = w & 1;

    f32x4 acc[2][4] = {};
    gemm_core8(Xh, Wt, As, Bs, acc, m0, n0, K, tid);

#pragma unroll
    for (int mi = 0; mi < 2; ++mi)
#pragma unroll
        for (int ni = 0; ni < 4; ++ni)
#pragma unroll
            for (int r = 0; r < 4; ++r) {
                int m = m0 + wr * 32 + mi * 16 + 4 * g + r;
                int n = n0 + wc * 64 + ni * 16 + c;
                outF[(size_t)m * N + n] = acc[mi][ni][r] + bias[n];
            }
}

// ---------------------------------------------------------------------------
// MFMA flash attention, R23: T15-style 2-deep pipeline.
// Triple-buffered K/V (pure-DMA staging); per iteration:
//   issue stage(t+2) -> QK(t+1) into the OTHER s4 bank -> softmax/PV(t)
//   -> barrier.  QK(t+1) MFMAs overlap softmax(t) VALU in the same stream.
// Lagged-max fix: growth branch also shifts the freshly computed s4(t+1).
// ---------------------------------------------------------------------------
__global__ __launch_bounds__(512, 4) void attn_mfma_kernel(
    const _Float16* __restrict__ Qh, const _Float16* __restrict__ Kh,
    const _Float16* __restrict__ Vt, _Float16* __restrict__ out)
{
    __shared__ _Float16 KsAll[3 * 64 * 64];   // 24KB
    __shared__ _Float16 VsAll[3 * 64 * 64];   // 24KB
    __shared__ _Float16 Ps[8][32 * 64];       // 32KB  -> 80KB total, 2 blk/CU

    const int tid = threadIdx.x;
    const int lane = tid & 63, w = tid >> 6;          // w in 0..7
    const int g = lane >> 4, c = lane & 15;
    int flat = blockIdx.x + 8 * blockIdx.y + 128 * blockIdx.z;
    int swz = (flat & 7) * 64 + (flat >> 3);          // 512/8 = 64
    const int q0 = (swz & 7) * 256;
    const int h = (swz >> 3) & 15;
    const int b = swz >> 7;
    const size_t hb = ((size_t)b * NUM_HEADS + h) * L_ * D_K;

    const int srow_ = w * 8 + (lane >> 3);
    const int scs_ = (lane & 7) ^ (srow_ & 7);

#define STAGE_K(kv0, buf)                                                     \
    do {                                                                      \
        const _Float16* src_ = &Kh[hb + (size_t)((kv0) + srow_) * D_K + 8 * scs_]; \
        __builtin_amdgcn_global_load_lds(                                     \
            (const __attribute__((address_space(1))) void*)src_,              \
            (__attribute__((address_space(3))) void*)&KsAll[(buf) * 4096 + w * 512], \
            16, 0, 0);                                                        \
    } while (0)

#define STAGE_V(kv0, buf)                                                     \
    do {                                                                      \
        const _Float16* src_ = &Vt[hb + (size_t)srow_ * L_ + (kv0) + 8 * scs_]; \
        __builtin_amdgcn_global_load_lds(                                     \
            (const __attribute__((address_space(1))) void*)src_,              \
            (__attribute__((address_space(3))) void*)&VsAll[(buf) * 4096 + w * 512], \
            16, 0, 0);                                                        \
    } while (0)

    // Q fragments: lane holds Q[q=c][8g..8g+7] per 16-row group
    f16x8 qf[2][2];
#pragma unroll
    for (int rg = 0; rg < 2; ++rg) {
        const size_t qrow = hb + (size_t)(q0 + 32 * w + 16 * rg + c) * D_K;
        qf[rg][0] = *(const f16x8*)&Qh[qrow + 8 * g];
        qf[rg][1] = *(const f16x8*)&Qh[qrow + 32 + 8 * g];
    }

    const f16x8 onesf = {(_Float16)1.f, (_Float16)1.f, (_Float16)1.f, (_Float16)1.f,
                         (_Float16)1.f, (_Float16)1.f, (_Float16)1.f, (_Float16)1.f};

    f32x4 o[2][4] = {};
    f32x4 l4[2] = {};
    float m_run[2] = {0.f, 0.f};       // log2-domain running max (lagged)

    const int NT = L_ / 64;            // 32, even
    _Float16* myP = &Ps[w][0];
    const int swzc = (c & 7) << 3;

    f32x4 s4A[2][4], s4B[2][4];

// QK into S4 from K buffer `bufi`, C seeded with -m_run
#define QK_STEP(S4, bufi)                                                     \
    do {                                                                      \
        const _Float16* Kc_ = &KsAll[(bufi) * 4096];                          \
        _Pragma("unroll") for (int rg = 0; rg < 2; ++rg) {                    \
            f32x4 mi_ = {-m_run[rg], -m_run[rg], -m_run[rg], -m_run[rg]};     \
            _Pragma("unroll") for (int ct = 0; ct < 4; ++ct) S4[rg][ct] = mi_; \
        }                                                                     \
        __builtin_amdgcn_s_setprio(1);                                        \
        _Pragma("unroll") for (int ct = 0; ct < 4; ++ct) {                    \
            int row_ = 16 * ct + c;                                           \
            int sz_ = (row_ & 7) << 3;                                        \
            f16x8 kf0_ = *(const f16x8*)&Kc_[row_ * 64 + ((8 * g) ^ sz_)];    \
            f16x8 kf1_ = *(const f16x8*)&Kc_[row_ * 64 + ((32 + 8 * g) ^ sz_)]; \
            _Pragma("unroll") for (int rg = 0; rg < 2; ++rg) {                \
                S4[rg][ct] = __builtin_amdgcn_mfma_f32_16x16x32_f16(kf0_, qf[rg][0], S4[rg][ct], 0, 0, 0); \
                S4[rg][ct] = __builtin_amdgcn_mfma_f32_16x16x32_f16(kf1_, qf[rg][1], S4[rg][ct], 0, 0, 0); \
            }                                                                 \
        }                                                                     \
        __builtin_amdgcn_s_setprio(0);                                        \
    } while (0)

// softmax + PV on S4 (tile in V buffer `bufi`); growth branch also patches S4N
#define SM_PV(S4, S4N, bufi)                                                  \
    do {                                                                      \
        const _Float16* Vc_ = &VsAll[(bufi) * 4096];                          \
        float vml_[2];                                                        \
        _Pragma("unroll") for (int rg = 0; rg < 2; ++rg) {                    \
            float m1_ = fmax3(S4[rg][0][0], S4[rg][0][1], S4[rg][0][2]);      \
            float m2_ = fmax3(S4[rg][0][3], S4[rg][1][0], S4[rg][1][1]);      \
            float m3_ = fmax3(S4[rg][1][2], S4[rg][1][3], S4[rg][2][0]);      \
            float m4_ = fmax3(S4[rg][2][1], S4[rg][2][2], S4[rg][2][3]);      \
            float m5_ = fmax3(S4[rg][3][0], S4[rg][3][1], S4[rg][3][2]);      \
            float t0_ = fmax3(m1_, m2_, S4[rg][3][3]);                        \
            float t1_ = fmax3(m3_, m4_, m5_);                                 \
            vml_[rg] = fmaxf(t0_, t1_);                                       \
        }                                                                     \
        int nog_ = (vml_[0] <= 8.f) && (vml_[1] <= 8.f);                      \
        if (!__all(nog_)) {                                                   \
            _Pragma("unroll") for (int rg = 0; rg < 2; ++rg) {                \
                float vm_ = vml_[rg];                                         \
                vm_ = fmaxf(vm_, __shfl_xor(vm_, 16));                        \
                vm_ = fmaxf(vm_, __shfl_xor(vm_, 32));                        \
                float delta_ = fmaxf(vm_, 0.f);                               \
                float fac_ = fexp2(-delta_);                                  \
                m_run[rg] += delta_;                                          \
                float facr_[4];                                               \
                _Pragma("unroll") for (int r = 0; r < 4; ++r) facr_[r] = __shfl(fac_, 4 * g + r); \
                _Pragma("unroll") for (int r = 0; r < 4; ++r) l4[rg][r] *= facr_[r]; \
                _Pragma("unroll") for (int dt = 0; dt < 4; ++dt)              \
                    _Pragma("unroll") for (int r = 0; r < 4; ++r) o[rg][dt][r] *= facr_[r]; \
                _Pragma("unroll") for (int ct = 0; ct < 4; ++ct)              \
                    _Pragma("unroll") for (int r = 0; r < 4; ++r) {           \
                        S4[rg][ct][r] -= delta_;                              \
                        S4N[rg][ct][r] -= delta_;                             \
                    }                                                         \
            }                                                                 \
        }                                                                     \
        _Pragma("unroll") for (int rg = 0; rg < 2; ++rg) {                    \
            _Pragma("unroll") for (int ct = 0; ct < 4; ++ct) {                \
                float p0_ = fexp2(S4[rg][ct][0]);                             \
                float p1_ = fexp2(S4[rg][ct][1]);                             \
                float p2_ = fexp2(S4[rg][ct][2]);                             \
                float p3_ = fexp2(S4[rg][ct][3]);                             \
                f16x4 pk_ = pack4(p0_, p1_, p2_, p3_);                        \
                *(f16x4*)&myP[(16 * rg + c) * 64 + ((16 * ct + 4 * g) ^ swzc)] = pk_; \
            }                                                                 \
        }                                                                     \
        f16x8 pa_[2][2];                                                      \
        _Pragma("unroll") for (int rg = 0; rg < 2; ++rg) {                    \
            int prow_ = 16 * rg + c;                                          \
            pa_[rg][0] = *(const f16x8*)&myP[prow_ * 64 + ((8 * g) ^ swzc)];  \
            pa_[rg][1] = *(const f16x8*)&myP[prow_ * 64 + ((32 + 8 * g) ^ swzc)]; \
        }                                                                     \
        __builtin_amdgcn_s_setprio(1);                                        \
        _Pragma("unroll") for (int rg = 0; rg < 2; ++rg) {                    \
            l4[rg] = __builtin_amdgcn_mfma_f32_16x16x32_f16(pa_[rg][0], onesf, l4[rg], 0, 0, 0); \
            l4[rg] = __builtin_amdgcn_mfma_f32_16x16x32_f16(pa_[rg][1], onesf, l4[rg], 0, 0, 0); \
        }                                                                     \
        _Pragma("unroll") for (int dt = 0; dt < 4; ++dt) {                    \
            int row_ = 16 * dt + c;                                           \
            int sz_ = (row_ & 7) << 3;                                        \
            f16x8 vf0_ = *(const f16x8*)&Vc_[row_ * 64 + ((8 * g) ^ sz_)];    \
            f16x8 vf1_ = *(const f16x8*)&Vc_[row_ * 64 + ((32 + 8 * g) ^ sz_)]; \
            _Pragma("unroll") for (int rg = 0; rg < 2; ++rg) {                \
                o[rg][dt] = __builtin_amdgcn_mfma_f32_16x16x32_f16(pa_[rg][0], vf0_, o[rg][dt], 0, 0, 0); \
                o[rg][dt] = __builtin_amdgcn_mfma_f32_16x16x32_f16(pa_[rg][1], vf1_, o[rg][dt], 0, 0, 0); \
            }                                                                 \
        }                                                                     \
        __builtin_amdgcn_s_setprio(0);                                        \
    } while (0)

    // ---- prologue ----
    STAGE_K(0, 0); STAGE_V(0, 0);
    __syncthreads();                       // buf0 ready
    STAGE_K(64, 1); STAGE_V(64, 1);        // tile 1 in flight
    QK_STEP(s4A, 0);                       // QK(0)
    __syncthreads();                       // buf1 ready (drains stage-1 DMAs)

    for (int tt = 0; tt < NT; tt += 2) {
        {   // t = tt : cur buf tt%3, compute QK(tt+1) into s4B
            int b2 = (tt + 2) % 3;
            int kv2 = (tt + 2 < NT) ? (tt + 2) * 64 : 0;
            STAGE_K(kv2, b2); STAGE_V(kv2, b2);
            QK_STEP(s4B, (tt + 1) % 3);    // tt+1 < NT always (NT even)
            SM_PV(s4A, s4B, tt % 3);
            __syncthreads();               // drains stage(tt+2); cur reusable
        }
        {   // t = tt+1 : cur buf (tt+1)%3, compute QK(tt+2) into s4A
            int t = tt + 1;
            int b2 = (t + 2) % 3;
            int kv2 = (t + 2 < NT) ? (t + 2) * 64 : 0;
            STAGE_K(kv2, b2); STAGE_V(kv2, b2);
            if (t + 1 < NT) QK_STEP(s4A, (t + 1) % 3);
            SM_PV(s4B, s4A, t % 3);
            __syncthreads();
        }
    }

    // ---- epilogue: l already in o-row layout ----
#pragma unroll
    for (int rg = 0; rg < 2; ++rg)
#pragma unroll
        for (int r = 0; r < 4; ++r) {
            float inv = 1.f / l4[rg][r];
            int q = q0 + 32 * w + 16 * rg + 4 * g + r;
#pragma unroll
            for (int dt = 0; dt < 4; ++dt)
                out[((size_t)b * L_ + q) * D_MODEL + h * D_K + 16 * dt + c] =
                    (_Float16)(o[rg][dt][r] * inv);
        }
#undef STAGE_K
#undef STAGE_V
#undef QK_STEP
#undef SM_PV
}

extern "C" void kernel_launch(void* const* d_in, const int* in_sizes, int n_in,
                              void* d_out, int out_size, void* d_ws, size_t ws_size,
                              hipStream_t stream) {
    const float* query = (const float*)d_in[0];
    const float* key   = (const float*)d_in[1];
    const float* value = (const float*)d_in[2];
    const float* wq = (const float*)d_in[4];
    const float* bq = (const float*)d_in[5];
    const float* wk = (const float*)d_in[6];
    const float* bk = (const float*)d_in[7];
    const float* wv = (const float*)d_in[8];
    const float* bv = (const float*)d_in[9];
    const float* wo = (const float*)d_in[10];
    const float* bo = (const float*)d_in[11];
    float* out = (float*)d_out;

    const size_t tok = (size_t)B_ * L_ * D_MODEL;   // 8.4M
    const size_t wsz = (size_t)D_MODEL * D_MODEL;   // 1M
    _Float16* qh = (_Float16*)d_ws;
    _Float16* kh = qh + tok;
    _Float16* vt = kh + tok;    // V^T: [b][h][dk][l]
    _Float16* oh = vt + tok;
    _Float16* wqt = oh + tok;
    _Float16* wkt = wqt + wsz;
    _Float16* wvt = wkt + wsz;
    _Float16* wot = wvt + wsz;

    const int M = B_ * L_;  // 8192
    dim3 blk(256);

    transp_cast4_kernel<<<dim3(16, 16, 4), blk, 0, stream>>>(
        wq, wk, wv, wo, wqt, wkt, wvt, wot);

    // Q scale folds 1/sqrt(64) * log2(e) -> attention works in base-2 domain
    gemm_qkv_kernel<<<dim3(D_MODEL / 128, M / 128, 3), dim3(512), 0, stream>>>(
        query, key, value, wqt, wkt, wvt, bq, bk, bv, qh, kh, vt,
        0.18033688011112042f);

    attn_mfma_kernel<<<dim3(L_ / 256, NUM_HEADS, B_), dim3(512), 0, stream>>>(
        qh, kh, vt, oh);

    gemm_o_kernel<<<dim3(D_MODEL / 128, M / 128), dim3(512), 0, stream>>>(
        oh, wot, bo, out, M, D_MODEL, D_MODEL);
}

// Round 24
// 200.408 us; speedup vs baseline: 1.7608x; 1.7608x over previous
//
#include <hip/hip_runtime.h>
#include <hip/hip_bf16.h>

#define D_MODEL 1024
#define NUM_HEADS 16
#define D_K 64
#define B_ 4
#define L_ 2048

typedef _Float16 f16x8 __attribute__((ext_vector_type(8)));
typedef _Float16 f16x4 __attribute__((ext_vector_type(4)));
typedef float f32x4 __attribute__((ext_vector_type(4)));

__device__ __forceinline__ float fexp2(float x) {
    float r;
    asm("v_exp_f32 %0, %1" : "=v"(r) : "v"(x));
    return r;
}

__device__ __forceinline__ float fmax3(float a, float b, float c) {
    float r;
    asm("v_max3_f32 %0, %1, %2, %3" : "=v"(r) : "v"(a), "v"(b), "v"(c));
    return r;
}

__device__ __forceinline__ f16x4 pack4(float p0, float p1, float p2, float p3) {
    auto lo = __builtin_amdgcn_cvt_pkrtz(p0, p1);
    auto hi = __builtin_amdgcn_cvt_pkrtz(p2, p3);
    f16x4 pk;
    pk[0] = (_Float16)lo[0]; pk[1] = (_Float16)lo[1];
    pk[2] = (_Float16)hi[0]; pk[3] = (_Float16)hi[1];
    return pk;
}

// ---------------------------------------------------------------------------
// W[k][n] fp32 -> Wt[n][k] fp16
// ---------------------------------------------------------------------------
__global__ __launch_bounds__(256) void transp_cast4_kernel(
    const float* __restrict__ w0, const float* __restrict__ w1,
    const float* __restrict__ w2, const float* __restrict__ w3,
    _Float16* __restrict__ t0, _Float16* __restrict__ t1,
    _Float16* __restrict__ t2, _Float16* __restrict__ t3)
{
    const float* W = blockIdx.z == 0 ? w0 : blockIdx.z == 1 ? w1
                   : blockIdx.z == 2 ? w2 : w3;
    _Float16* Wt = blockIdx.z == 0 ? t0 : blockIdx.z == 1 ? t1
                 : blockIdx.z == 2 ? t2 : t3;
    __shared__ _Float16 Ls[64][72];
    const int n0 = blockIdx.x * 64, k0 = blockIdx.y * 64;
    const int tid = threadIdx.x;
#pragma unroll
    for (int i = 0; i < 4; ++i) {
        int idx = tid + 256 * i;
        int k = idx >> 4, c4 = (idx & 15) << 2;
        float4 wv = *(const float4*)&W[(size_t)(k0 + k) * D_MODEL + n0 + c4];
        Ls[c4 + 0][k] = (_Float16)wv.x;
        Ls[c4 + 1][k] = (_Float16)wv.y;
        Ls[c4 + 2][k] = (_Float16)wv.z;
        Ls[c4 + 3][k] = (_Float16)wv.w;
    }
    __syncthreads();
#pragma unroll
    for (int i = 0; i < 2; ++i) {
        int idx = tid + 256 * i;
        int n = idx >> 3, k8 = (idx & 7) << 3;
        f16x8 v;
#pragma unroll
        for (int j = 0; j < 8; ++j) v[j] = Ls[n][k8 + j];
        *(f16x8*)&Wt[(size_t)(n0 + n) * D_MODEL + k0 + k8] = v;
    }
}

// ---------------------------------------------------------------------------
// MFMA GEMM core, 512 thr / 8 waves, 128x128 tile, fused fp32-A cast,
// B double-buffered with issue-early.
// ---------------------------------------------------------------------------
__device__ __forceinline__ void gemm_core_f32A8(
    const float* __restrict__ X, const _Float16* __restrict__ Wt,
    _Float16* As, _Float16* Bs0, _Float16* Bs1, f32x4 (&acc)[2][4],
    int m0, int n0, int K, int tid)
{
    const int lane = tid & 63, w = tid >> 6;      // w 0..7
    const int g = lane >> 4, c = lane & 15;
    const int wr = w >> 1, wc = w & 1;            // wr 0..3, wc 0..1
    const int srow = lane >> 3, sslot = lane & 7;
    const int gslot = (sslot ^ (srow & 7)) << 3;

    // prologue: A regs for kt=0, B DMA for kt=0 -> Bs0
    float4 ar[2][2];
#pragma unroll
    for (int i = 0; i < 2; ++i) {
        int r = (w * 2 + i) * 8 + srow;
        const float* xp = &X[(size_t)(m0 + r) * K + 8 * sslot];
        ar[i][0] = *(const float4*)xp;
        ar[i][1] = *(const float4*)(xp + 4);
    }
#pragma unroll
    for (int i = 0; i < 2; ++i) {
        int chunk = w * 2 + i;                    // 16 chunks x 8 rows = 128
        int r = chunk * 8 + srow;
        const _Float16* gq = &Wt[(size_t)(n0 + r) * K + gslot];
        __builtin_amdgcn_global_load_lds(
            (const __attribute__((address_space(1))) void*)gq,
            (__attribute__((address_space(3))) void*)&Bs0[chunk * 512],
            16, 0, 0);
    }

    for (int kt = 0; kt < K; kt += 64) {
        _Float16* Bcur = ((kt >> 6) & 1) ? Bs1 : Bs0;
        _Float16* Bnxt = ((kt >> 6) & 1) ? Bs0 : Bs1;

        // A: cvt regs (loaded last iter) + swizzled ds_write_b128
#pragma unroll
        for (int i = 0; i < 2; ++i) {
            int r = (w * 2 + i) * 8 + srow;
            f16x4 ca = pack4(ar[i][0].x, ar[i][0].y, ar[i][0].z, ar[i][0].w);
            f16x4 cb = pack4(ar[i][1].x, ar[i][1].y, ar[i][1].z, ar[i][1].w);
            f16x8 cc;
            cc[0] = ca[0]; cc[1] = ca[1]; cc[2] = ca[2]; cc[3] = ca[3];
            cc[4] = cb[0]; cc[5] = cb[1]; cc[6] = cb[2]; cc[7] = cb[3];
            *(f16x8*)&As[r * 64 + ((sslot ^ (r & 7)) << 3)] = cc;
        }
        __syncthreads();   // #1: Bcur DMA drained + As writes visible

        // issue next step's B DMA (other buffer) and A fp32 loads
        int ktn = kt + 64;
        if (ktn < K) {
#pragma unroll
            for (int i = 0; i < 2; ++i) {
                int chunk = w * 2 + i;
                int r = chunk * 8 + srow;
                const _Float16* gq = &Wt[(size_t)(n0 + r) * K + ktn + gslot];
                __builtin_amdgcn_global_load_lds(
                    (const __attribute__((address_space(1))) void*)gq,
                    (__attribute__((address_space(3))) void*)&Bnxt[chunk * 512],
                    16, 0, 0);
            }
#pragma unroll
            for (int i = 0; i < 2; ++i) {
                int r = (w * 2 + i) * 8 + srow;
                const float* xp = &X[(size_t)(m0 + r) * K + ktn + 8 * sslot];
                ar[i][0] = *(const float4*)xp;
                ar[i][1] = *(const float4*)(xp + 4);
            }
        }

#pragma unroll
        for (int kk = 0; kk < 2; ++kk) {
            f16x8 a[2], bf[4];
#pragma unroll
            for (int mi = 0; mi < 2; ++mi) {
                int row = wr * 32 + mi * 16 + c;
                int ks = kk * 4 + g;
                a[mi] = *(const f16x8*)&As[row * 64 + ((ks ^ (row & 7)) << 3)];
            }
#pragma unroll
            for (int ni = 0; ni < 4; ++ni) {
                int row = wc * 64 + ni * 16 + c;
                int ks = kk * 4 + g;
                bf[ni] = *(const f16x8*)&Bcur[row * 64 + ((ks ^ (row & 7)) << 3)];
            }
#pragma unroll
            for (int mi = 0; mi < 2; ++mi)
#pragma unroll
                for (int ni = 0; ni < 4; ++ni)
                    acc[mi][ni] = __builtin_amdgcn_mfma_f32_16x16x32_f16(
                        a[mi], bf[ni], acc[mi][ni], 0, 0, 0);
        }
        __syncthreads();   // #2: As/Bcur reads done before next overwrite
    }
}

// ---------------------------------------------------------------------------
// fp16-A GEMM core, 512 thr / 8 waves, 128x128 (for the O projection)
// ---------------------------------------------------------------------------
__device__ __forceinline__ void gemm_core8(
    const _Float16* __restrict__ Xh, const _Float16* __restrict__ Wt,
    _Float16* As, _Float16* Bs, f32x4 (&acc)[2][4],
    int m0, int n0, int K, int tid)
{
    const int lane = tid & 63, w = tid >> 6;
    const int g = lane >> 4, c = lane & 15;
    const int wr = w >> 1, wc = w & 1;
    const int srow = lane >> 3, sslot = lane & 7;
    const int gslot = (sslot ^ (srow & 7)) << 3;

    for (int kt = 0; kt < K; kt += 64) {
#pragma unroll
        for (int i = 0; i < 2; ++i) {
            int chunk = w * 2 + i;
            int r = chunk * 8 + srow;
            const _Float16* gp = &Xh[(size_t)(m0 + r) * K + kt + gslot];
            __builtin_amdgcn_global_load_lds(
                (const __attribute__((address_space(1))) void*)gp,
                (__attribute__((address_space(3))) void*)&As[chunk * 512],
                16, 0, 0);
            const _Float16* gq = &Wt[(size_t)(n0 + r) * K + kt + gslot];
            __builtin_amdgcn_global_load_lds(
                (const __attribute__((address_space(1))) void*)gq,
                (__attribute__((address_space(3))) void*)&Bs[chunk * 512],
                16, 0, 0);
        }
        __syncthreads();

#pragma unroll
        for (int kk = 0; kk < 2; ++kk) {
            f16x8 a[2], bf[4];
#pragma unroll
            for (int mi = 0; mi < 2; ++mi) {
                int row = wr * 32 + mi * 16 + c;
                int ks = kk * 4 + g;
                a[mi] = *(const f16x8*)&As[row * 64 + ((ks ^ (row & 7)) << 3)];
            }
#pragma unroll
            for (int ni = 0; ni < 4; ++ni) {
                int row = wc * 64 + ni * 16 + c;
                int ks = kk * 4 + g;
                bf[ni] = *(const f16x8*)&Bs[row * 64 + ((ks ^ (row & 7)) << 3)];
            }
#pragma unroll
            for (int mi = 0; mi < 2; ++mi)
#pragma unroll
                for (int ni = 0; ni < 4; ++ni)
                    acc[mi][ni] = __builtin_amdgcn_mfma_f32_16x16x32_f16(
                        a[mi], bf[ni], acc[mi][ni], 0, 0, 0);
        }
        __syncthreads();
    }
}

// ---------------------------------------------------------------------------
// Merged Q/K/V projection GEMMs, 512 thr / 8 waves, fused cast + dbuf-B.
// grid (8,64,3) -> flat 1536, XCD-bijective swizzle (1536/8 = 192).
// Q,K: head-split [b][h][l][dk]. V: transposed -> [b][h][dk][l].
// ---------------------------------------------------------------------------
__global__ __launch_bounds__(512, 4) void gemm_qkv_kernel(
    const float* __restrict__ xq, const float* __restrict__ xk,
    const float* __restrict__ xv, const _Float16* __restrict__ wqt,
    const _Float16* __restrict__ wkt, const _Float16* __restrict__ wvt,
    const float* __restrict__ bq, const float* __restrict__ bk,
    const float* __restrict__ bv, _Float16* __restrict__ qh,
    _Float16* __restrict__ kh, _Float16* __restrict__ vt, float qscale)
{
    __shared__ _Float16 LB[128 * 192];   // As | Bs0 | Bs1 (48KB); transpose reuses 32KB
    _Float16* As = LB;
    _Float16* Bs0 = LB + 128 * 64;
    _Float16* Bs1 = LB + 128 * 128;

    int flat = blockIdx.x + 8 * blockIdx.y + 512 * blockIdx.z;
    int swz = (flat & 7) * 192 + (flat >> 3);     // 1536/8 = 192
    const int n0 = (swz & 7) * 128;
    const int m0 = ((swz >> 3) & 63) * 128;
    const int z = swz >> 9;

    const float* X = z == 0 ? xq : z == 1 ? xk : xv;
    const _Float16* Wt = z == 0 ? wqt : z == 1 ? wkt : wvt;
    const float* bias = z == 0 ? bq : z == 1 ? bk : bv;

    const int tid = threadIdx.x;
    const int lane = tid & 63, w = tid >> 6;
    const int g = lane >> 4, c = lane & 15;
    const int wr = w >> 1, wc = w & 1;

    f32x4 acc[2][4] = {};
    gemm_core_f32A8(X, Wt, As, Bs0, Bs1, acc, m0, n0, D_MODEL, tid);

    if (z != 2) {
        _Float16* outH = z == 0 ? qh : kh;
        const float scale = z == 0 ? qscale : 1.0f;
#pragma unroll
        for (int mi = 0; mi < 2; ++mi)
#pragma unroll
            for (int ni = 0; ni < 4; ++ni)
#pragma unroll
                for (int r = 0; r < 4; ++r) {
                    int m = m0 + wr * 32 + mi * 16 + 4 * g + r;
                    int n = n0 + wc * 64 + ni * 16 + c;
                    float v = (acc[mi][ni][r] + bias[n]) * scale;
                    int b = m >> 11, l = m & (L_ - 1);
                    int hh = n >> 6, dk = n & 63;
                    outH[(((size_t)b * NUM_HEADS + hh) * L_ + l) * D_K + dk] =
                        (_Float16)v;
                }
    } else {
        __syncthreads();   // done with As/Bs before reusing LB
        // LB reused as [128 n][128 m] f16 (32KB), swizzled
#pragma unroll
        for (int mi = 0; mi < 2; ++mi)
#pragma unroll
            for (int ni = 0; ni < 4; ++ni)
#pragma unroll
                for (int r = 0; r < 4; ++r) {
                    int ml = wr * 32 + mi * 16 + 4 * g + r;
                    int nl = wc * 64 + ni * 16 + c;
                    LB[nl * 128 + (ml ^ ((nl & 7) << 3))] =
                        (_Float16)(acc[mi][ni][r] + bias[n0 + nl]);
                }
        __syncthreads();
#pragma unroll
        for (int it = 0; it < 4; ++it) {
            int chunk = tid + 512 * it;          // 0..2047
            int nl = chunk >> 4;                 // 0..127
            int mc = (chunk & 15) << 3;          // 0..120
            f16x8 vv = *(const f16x8*)&LB[nl * 128 + (mc ^ ((nl & 7) << 3))];
            int n = n0 + nl;
            int hh = n >> 6, dk = n & 63;
            int mstart = m0 + mc;
            int bb = mstart >> 11, l = mstart & (L_ - 1);
            *(f16x8*)&vt[(((size_t)bb * NUM_HEADS + hh) * D_K + dk) * L_ + l] = vv;
        }
    }
}

// ---------------------------------------------------------------------------
// O-projection GEMM, 512 thr / 8 waves (XCD-swizzled), fp32 flat output
// ---------------------------------------------------------------------------
__global__ __launch_bounds__(512, 4) void gemm_o_kernel(
    const _Float16* __restrict__ Xh, const _Float16* __restrict__ Wt,
    const float* __restrict__ bias, float* __restrict__ outF, int M, int N, int K)
{
    __shared__ _Float16 As[128 * 64];
    __shared__ _Float16 Bs[128 * 64];
    int flat = blockIdx.x + 8 * blockIdx.y;
    int swz = (flat & 7) * 64 + (flat >> 3);
    const int n0 = (swz & 7) * 128;
    const int m0 = (swz >> 3) * 128;

    const int tid = threadIdx.x;
    const int lane = tid & 63, w = tid >> 6;
    const int g = lane >> 4, c = lane & 15;
    const int wr = w >> 1, wc = w & 1;

    f32x4 acc[2][4] = {};
    gemm_core8(Xh, Wt, As, Bs, acc, m0, n0, K, tid);

#pragma unroll
    for (int mi = 0; mi < 2; ++mi)
#pragma unroll
        for (int ni = 0; ni < 4; ++ni)
#pragma unroll
            for (int r = 0; r < 4; ++r) {
                int m = m0 + wr * 32 + mi * 16 + 4 * g + r;
                int n = n0 + wc * 64 + ni * 16 + c;
                outF[(size_t)m * N + n] = acc[mi][ni][r] + bias[n];
            }
}

// ---------------------------------------------------------------------------
// MFMA flash attention (R22 version, restored): BOTH K and V staged via
// global_load_lds (linear dest + inverse-swizzled source), ONE barrier per
// tile; C-init = -m, MFMA row-sum, max3 tree, lane-local defer check.
// ---------------------------------------------------------------------------
__global__ __launch_bounds__(512, 4) void attn_mfma_kernel(
    const _Float16* __restrict__ Qh, const _Float16* __restrict__ Kh,
    const _Float16* __restrict__ Vt, _Float16* __restrict__ out)
{
    __shared__ _Float16 Ks[2][64 * 64];
    __shared__ _Float16 VsT[2][64 * 64];
    __shared__ _Float16 Ps[8][32 * 64];

    const int tid = threadIdx.x;
    const int lane = tid & 63, w = tid >> 6;          // w in 0..7
    const int g = lane >> 4, c = lane & 15;
    int flat = blockIdx.x + 8 * blockIdx.y + 128 * blockIdx.z;
    int swz = (flat & 7) * 64 + (flat >> 3);          // 512/8 = 64
    const int q0 = (swz & 7) * 256;
    const int h = (swz >> 3) & 15;
    const int b = swz >> 7;
    const size_t hb = ((size_t)b * NUM_HEADS + h) * L_ * D_K;

    const int srow_ = w * 8 + (lane >> 3);
    const int scs_ = (lane & 7) ^ (srow_ & 7);

#define STAGE_K(kv0, buf)                                                     \
    do {                                                                      \
        const _Float16* src_ = &Kh[hb + (size_t)((kv0) + srow_) * D_K + 8 * scs_]; \
        __builtin_amdgcn_global_load_lds(                                     \
            (const __attribute__((address_space(1))) void*)src_,              \
            (__attribute__((address_space(3))) void*)&Ks[buf][w * 512],       \
            16, 0, 0);                                                        \
    } while (0)

#define STAGE_V(kv0, buf)                                                     \
    do {                                                                      \
        const _Float16* src_ = &Vt[hb + (size_t)srow_ * L_ + (kv0) + 8 * scs_]; \
        __builtin_amdgcn_global_load_lds(                                     \
            (const __attribute__((address_space(1))) void*)src_,              \
            (__attribute__((address_space(3))) void*)&VsT[buf][w * 512],      \
            16, 0, 0);                                                        \
    } while (0)

    // Q fragments: lane holds Q[q=c][8g..8g+7] per 16-row group
    f16x8 qf[2][2];
#pragma unroll
    for (int rg = 0; rg < 2; ++rg) {
        const size_t qrow = hb + (size_t)(q0 + 32 * w + 16 * rg + c) * D_K;
        qf[rg][0] = *(const f16x8*)&Qh[qrow + 8 * g];
        qf[rg][1] = *(const f16x8*)&Qh[qrow + 32 + 8 * g];
    }

    const f16x8 onesf = {(_Float16)1.f, (_Float16)1.f, (_Float16)1.f, (_Float16)1.f,
                         (_Float16)1.f, (_Float16)1.f, (_Float16)1.f, (_Float16)1.f};

    f32x4 o[2][4] = {};
    f32x4 l4[2] = {};                  // row-sums of P via MFMA, o-row layout
    float m_run[2] = {0.f, 0.f};       // log2-domain running max (lagged)

    const int NT = L_ / 64;
    _Float16* myP = &Ps[w][0];
    const int swzc = (c & 7) << 3;

    // prologue: stage tile 0 (both K and V via DMA), single drain
    STAGE_K(0, 0);
    STAGE_V(0, 0);
    __syncthreads();

    for (int t = 0; t < NT; ++t) {
        const int cur = t & 1, nb = (t + 1) & 1;

        // ---- issue next tile's K/V DMAs into the other buffer ----
        int nxt = (t + 1 < NT) ? (t + 1) * 64 : 0;
        STAGE_K(nxt, nb);
        STAGE_V(nxt, nb);

        const _Float16* Kc = Ks[cur];
        const _Float16* Vc = VsT[cur];

        // ---- S^T - m = K Q^T + C(-m) : lane holds (S-m)[key=16ct+4g+r][q=c]
        f32x4 s4[2][4];
#pragma unroll
        for (int rg = 0; rg < 2; ++rg) {
            f32x4 minit = {-m_run[rg], -m_run[rg], -m_run[rg], -m_run[rg]};
#pragma unroll
            for (int ct = 0; ct < 4; ++ct) s4[rg][ct] = minit;
        }
        __builtin_amdgcn_s_setprio(1);
#pragma unroll
        for (int ct = 0; ct < 4; ++ct) {
            int row = 16 * ct + c;
            int swz2 = (row & 7) << 3;
            f16x8 kf0 = *(const f16x8*)&Kc[row * 64 + ((8 * g) ^ swz2)];
            f16x8 kf1 = *(const f16x8*)&Kc[row * 64 + ((32 + 8 * g) ^ swz2)];
#pragma unroll
            for (int rg = 0; rg < 2; ++rg) {
                s4[rg][ct] = __builtin_amdgcn_mfma_f32_16x16x32_f16(kf0, qf[rg][0], s4[rg][ct], 0, 0, 0);
                s4[rg][ct] = __builtin_amdgcn_mfma_f32_16x16x32_f16(kf1, qf[rg][1], s4[rg][ct], 0, 0, 0);
            }
        }
        __builtin_amdgcn_s_setprio(0);

        // ---- lane-local shifted max; cross-lane reduce only on growth ----
        float vml[2];
#pragma unroll
        for (int rg = 0; rg < 2; ++rg) {
            float m1 = fmax3(s4[rg][0][0], s4[rg][0][1], s4[rg][0][2]);
            float m2 = fmax3(s4[rg][0][3], s4[rg][1][0], s4[rg][1][1]);
            float m3 = fmax3(s4[rg][1][2], s4[rg][1][3], s4[rg][2][0]);
            float m4 = fmax3(s4[rg][2][1], s4[rg][2][2], s4[rg][2][3]);
            float m5 = fmax3(s4[rg][3][0], s4[rg][3][1], s4[rg][3][2]);
            float t0 = fmax3(m1, m2, s4[rg][3][3]);
            float t1 = fmax3(m3, m4, m5);
            vml[rg] = fmaxf(t0, t1);
        }
        int nog = (vml[0] <= 8.f) && (vml[1] <= 8.f);
        if (!__all(nog)) {
            // rare: full per-row reduction, absorb growth, rescale l/o
#pragma unroll
            for (int rg = 0; rg < 2; ++rg) {
                float vm = vml[rg];
                vm = fmaxf(vm, __shfl_xor(vm, 16));
                vm = fmaxf(vm, __shfl_xor(vm, 32));
                float delta = fmaxf(vm, 0.f);
                float fac = fexp2(-delta);
                m_run[rg] += delta;
                float facr[4];
#pragma unroll
                for (int r = 0; r < 4; ++r) facr[r] = __shfl(fac, 4 * g + r);
#pragma unroll
                for (int r = 0; r < 4; ++r) l4[rg][r] *= facr[r];
#pragma unroll
                for (int dt = 0; dt < 4; ++dt)
#pragma unroll
                    for (int r = 0; r < 4; ++r) o[rg][dt][r] *= facr[r];
#pragma unroll
                for (int ct = 0; ct < 4; ++ct)
#pragma unroll
                    for (int r = 0; r < 4; ++r) s4[rg][ct][r] -= delta;
            }
        }

        // ---- P = exp2(s4) directly (no sub in common path) ----
#pragma unroll
        for (int rg = 0; rg < 2; ++rg) {
#pragma unroll
            for (int ct = 0; ct < 4; ++ct) {
                float p0 = fexp2(s4[rg][ct][0]);
                float p1 = fexp2(s4[rg][ct][1]);
                float p2 = fexp2(s4[rg][ct][2]);
                float p3 = fexp2(s4[rg][ct][3]);
                f16x4 pk = pack4(p0, p1, p2, p3);
                *(f16x4*)&myP[(16 * rg + c) * 64 + ((16 * ct + 4 * g) ^ swzc)] = pk;
            }
        }

        // ---- O += P V ; l += P 1 (row-sum via MFMA) ----
        f16x8 pa[2][2];
#pragma unroll
        for (int rg = 0; rg < 2; ++rg) {
            int prow = 16 * rg + c;
            pa[rg][0] = *(const f16x8*)&myP[prow * 64 + ((8 * g) ^ swzc)];
            pa[rg][1] = *(const f16x8*)&myP[prow * 64 + ((32 + 8 * g) ^ swzc)];
        }
        __builtin_amdgcn_s_setprio(1);
#pragma unroll
        for (int rg = 0; rg < 2; ++rg) {
            l4[rg] = __builtin_amdgcn_mfma_f32_16x16x32_f16(pa[rg][0], onesf, l4[rg], 0, 0, 0);
            l4[rg] = __builtin_amdgcn_mfma_f32_16x16x32_f16(pa[rg][1], onesf, l4[rg], 0, 0, 0);
        }
#pragma unroll
        for (int dt = 0; dt < 4; ++dt) {
            int row = 16 * dt + c;
            int swz2 = (row & 7) << 3;
            f16x8 vf0 = *(const f16x8*)&Vc[row * 64 + ((8 * g) ^ swz2)];
            f16x8 vf1 = *(const f16x8*)&Vc[row * 64 + ((32 + 8 * g) ^ swz2)];
#pragma unroll
            for (int rg = 0; rg < 2; ++rg) {
                o[rg][dt] = __builtin_amdgcn_mfma_f32_16x16x32_f16(pa[rg][0], vf0, o[rg][dt], 0, 0, 0);
                o[rg][dt] = __builtin_amdgcn_mfma_f32_16x16x32_f16(pa[rg][1], vf1, o[rg][dt], 0, 0, 0);
            }
        }
        __builtin_amdgcn_s_setprio(0);

        // ---- single barrier: drains this tile's DMAs AND closes reads ----
        __syncthreads();
    }

    // ---- epilogue: l already in o-row layout ----
#pragma unroll
    for (int rg = 0; rg < 2; ++rg)
#pragma unroll
        for (int r = 0; r < 4; ++r) {
            float inv = 1.f / l4[rg][r];
            int q = q0 + 32 * w + 16 * rg + 4 * g + r;
#pragma unroll
            for (int dt = 0; dt < 4; ++dt)
                out[((size_t)b * L_ + q) * D_MODEL + h * D_K + 16 * dt + c] =
                    (_Float16)(o[rg][dt][r] * inv);
        }
#undef STAGE_K
#undef STAGE_V
}

extern "C" void kernel_launch(void* const* d_in, const int* in_sizes, int n_in,
                              void* d_out, int out_size, void* d_ws, size_t ws_size,
                              hipStream_t stream) {
    const float* query = (const float*)d_in[0];
    const float* key   = (const float*)d_in[1];
    const float* value = (const float*)d_in[2];
    const float* wq = (const float*)d_in[4];
    const float* bq = (const float*)d_in[5];
    const float* wk = (const float*)d_in[6];
    const float* bk = (const float*)d_in[7];
    const float* wv = (const float*)d_in[8];
    const float* bv = (const float*)d_in[9];
    const float* wo = (const float*)d_in[10];
    const float* bo = (const float*)d_in[11];
    float* out = (float*)d_out;

    const size_t tok = (size_t)B_ * L_ * D_MODEL;   // 8.4M
    const size_t wsz = (size_t)D_MODEL * D_MODEL;   // 1M
    _Float16* qh = (_Float16*)d_ws;
    _Float16* kh = qh + tok;
    _Float16* vt = kh + tok;    // V^T: [b][h][dk][l]
    _Float16* oh = vt + tok;
    _Float16* wqt = oh + tok;
    _Float16* wkt = wqt + wsz;
    _Float16* wvt = wkt + wsz;
    _Float16* wot = wvt + wsz;

    const int M = B_ * L_;  // 8192
    dim3 blk(256);

    transp_cast4_kernel<<<dim3(16, 16, 4), blk, 0, stream>>>(
        wq, wk, wv, wo, wqt, wkt, wvt, wot);

    // Q scale folds 1/sqrt(64) * log2(e) -> attention works in base-2 domain
    gemm_qkv_kernel<<<dim3(D_MODEL / 128, M / 128, 3), dim3(512), 0, stream>>>(
        query, key, value, wqt, wkt, wvt, bq, bk, bv, qh, kh, vt,
        0.18033688011112042f);

    attn_mfma_kernel<<<dim3(L_ / 256, NUM_HEADS, B_), dim3(512), 0, stream>>>(
        qh, kh, vt, oh);

    gemm_o_kernel<<<dim3(D_MODEL / 128, M / 128), dim3(512), 0, stream>>>(
        oh, wot, bo, out, M, D_MODEL, D_MODEL);
}